// Round 26
// baseline (762.699 us; speedup 1.0000x reference)
//
#include <hip/hip_runtime.h>
#include <cstdint>
#include <cmath>

typedef __bf16 bf16;
typedef __bf16 bf16x8 __attribute__((ext_vector_type(8)));
typedef __bf16 bf16x4 __attribute__((ext_vector_type(4)));
typedef float f32x4 __attribute__((ext_vector_type(4)));

#define B_ 2
#define S_ 2048
#define H_ 4096
#define NH 32
#define HD 128

#define VMCNT(n) asm volatile("s_waitcnt vmcnt(" #n ")" ::: "memory")
#define BAR() __builtin_amdgcn_s_barrier()

__device__ __forceinline__ void gl_lds16(const void* g, void* l) {
  __builtin_amdgcn_global_load_lds(
      (const __attribute__((address_space(1))) unsigned int*)g,
      (__attribute__((address_space(3))) unsigned int*)l, 16, 0, 0);
}

// ---------------- fused cast f32 -> bf16 (4 tensors in one launch) ----------------
__global__ __launch_bounds__(256) void cast4_kernel(const float* __restrict__ s0,
                                                    bf16* __restrict__ d0,
                                                    const float* __restrict__ s1,
                                                    bf16* __restrict__ d1,
                                                    const float* __restrict__ s2,
                                                    bf16* __restrict__ d2,
                                                    const float* __restrict__ s3,
                                                    bf16* __restrict__ d3, int n4) {
  int g = blockIdx.y;
  const float* in = (g == 0) ? s0 : (g == 1) ? s1 : (g == 2) ? s2 : s3;
  bf16* out = (g == 0) ? d0 : (g == 1) ? d1 : (g == 2) ? d2 : d3;
  int i = blockIdx.x * 256 + threadIdx.x;
  if (i < n4) {
    float4 v = ((const float4*)in)[i];
    bf16x4 o = {(bf16)v.x, (bf16)v.y, (bf16)v.z, (bf16)v.w};
    ((bf16x4*)out)[i] = o;
  }
}

__global__ __launch_bounds__(256) void cast_kernel(const float* __restrict__ in,
                                                   bf16* __restrict__ out, int n4) {
  int i = blockIdx.x * 256 + threadIdx.x;
  if (i < n4) {
    float4 v = ((const float4*)in)[i];
    bf16x4 o = {(bf16)v.x, (bf16)v.y, (bf16)v.z, (bf16)v.w};
    ((bf16x4*)out)[i] = o;
  }
}

// ---------------- shared MFMA quad ----------------
template <int TM, int TN>
__device__ __forceinline__ void mfma_q(f32x4 (&acc)[8][4], bf16x8 (&a)[4][2],
                                       bf16x8 (&b)[2][2]) {
  __builtin_amdgcn_s_setprio(1);
#pragma unroll
  for (int i = 0; i < 4; ++i)
#pragma unroll
    for (int j = 0; j < 2; ++j)
#pragma unroll
      for (int kf = 0; kf < 2; ++kf)
        acc[TM * 4 + i][TN * 2 + j] = __builtin_amdgcn_mfma_f32_16x16x32_bf16(
            a[i][kf], b[j][kf], acc[TM * 4 + i][TN * 2 + j], 0, 0, 0);
  __builtin_amdgcn_s_setprio(0);
}

// ---------------- persistent 256x256 QKV GEMM: grid 256, 3 col-tiles per block ----------------
// 1 block/CU (zero inter-block boundaries). Per tile: verified r24 relaxed-sync
// schedule. Boundary: tail drain -> epilogue (stores overlap next prologue's
// load latency) -> restage prologue -> VMCNT(4) (stores are "older" ops, counted
// correctly). g==2 writes V^T directly (Vt[bh][d][s], 8B bf16x4 stores).
__global__ __launch_bounds__(512, 2) void gemm256_qkv(const bf16* __restrict__ A,
                                                      const bf16* __restrict__ B0g,
                                                      const bf16* __restrict__ B1g,
                                                      const bf16* __restrict__ B2g,
                                                      bf16* __restrict__ C0g,
                                                      bf16* __restrict__ C1g,
                                                      bf16* __restrict__ C2g) {
  constexpr int K = 4096, N = 4096, KT = K / 64;
  __shared__ __attribute__((aligned(16))) char lds[131072];
  char* Al = lds;
  char* Bl = lds + 65536;
  int tid = threadIdx.x;
  int l = tid & 63, lr = l & 15, lg = l >> 4;
  int w = tid >> 6, wm = w >> 2, wn = w & 3;
  int bid = (int)blockIdx.x;
  int x = bid & 7, local = bid >> 3;   // 8 XCDs x 32 blocks
  int lr0b = local >> 4, cp = local & 15;
  int r0 = (x * 2 + lr0b) * 256;       // A panel L2-resident per XCD (r22 mapping)
  const bf16* Ab = A + (size_t)r0 * K;

  int lr0 = tid >> 3;
  int cel = (((tid & 7) ^ ((tid >> 3) & 7)) << 3);

  auto stageA = [&](int buf, int mh, int k0) {
    char* dst = Al + buf * 32768 + mh * 16384 + tid * 16;
    int ra = mh * 64 + lr0;
    gl_lds16(Ab + (size_t)ra * K + k0 + cel, dst);
    gl_lds16(Ab + (size_t)(ra + 128) * K + k0 + cel, dst + 8192);
  };
  auto stageB = [&](const bf16* Bb, int buf, int nh, int k0) {
    char* dst = Bl + buf * 32768 + nh * 16384 + tid * 16;
    int n0 = (lr0 >> 5) * 64 + nh * 32 + (lr0 & 31);
    gl_lds16(Bb + (size_t)n0 * K + k0 + cel, dst);
    gl_lds16(Bb + (size_t)(n0 + 128) * K + k0 + cel, dst + 8192);
  };

  int rsw = (lr & 7) << 4;
  auto ldA = [&](bf16x8 (&dst)[4][2], int buf, int mh) {
    char* base = Al + buf * 32768 + mh * 16384 + wm * 8192;
#pragma unroll
    for (int mfl = 0; mfl < 4; ++mfl)
#pragma unroll
      for (int kf = 0; kf < 2; ++kf)
        __builtin_memcpy(&dst[mfl][kf],
                         base + (mfl * 16 + lr) * 128 + ((kf * 64 + lg * 16) ^ rsw), 16);
  };
  auto ldB = [&](bf16x8 (&dst)[2][2], int buf, int nh) {
    char* base = Bl + buf * 32768 + nh * 16384 + wn * 4096;
#pragma unroll
    for (int nfl = 0; nfl < 2; ++nfl)
#pragma unroll
      for (int kf = 0; kf < 2; ++kf)
        __builtin_memcpy(&dst[nfl][kf],
                         base + (nfl * 16 + lr) * 128 + ((kf * 64 + lg * 16) ^ rsw), 16);
  };

  bf16x8 af[4][2], bf0[2][2], bf1[2][2];
  f32x4 acc[8][4];

  for (int tt = 0; tt < 3; ++tt) {
    int lc0 = cp * 3 + tt;
    int g = lc0 >> 4;
    int c0 = (lc0 & 15) * 256;
    const bf16* Bw = (g == 0) ? B0g : ((g == 1) ? B1g : B2g);
    const bf16* Bb = Bw + (size_t)c0 * K;

#pragma unroll
    for (int mf = 0; mf < 8; ++mf)
#pragma unroll
      for (int nf = 0; nf < 4; ++nf) acc[mf][nf] = f32x4{0.f, 0.f, 0.f, 0.f};

    // prologue (stores from previous tile's epilogue are "older" vmem ops;
    // VMCNT(4) drains them + A0,B0 -> entry invariant holds)
    stageA(0, 0, 0);
    stageB(Bb, 0, 0, 0);
    stageB(Bb, 0, 1, 0);
    stageA(0, 1, 0);
    VMCNT(4); BAR();

    for (int kt = 0; kt < KT - 1; ++kt) {
      int buf = kt & 1, nb = buf ^ 1;
      int k0n = (kt + 1) * 64;
      ldA(af, buf, 0);
      ldB(bf0, buf, 0);
      stageA(nb, 0, k0n);
      stageB(Bb, nb, 0, k0n);
      mfma_q<0, 0>(acc, af, bf0);
      VMCNT(4); BAR();
      ldB(bf1, buf, 1);
      stageB(Bb, nb, 1, k0n);
      mfma_q<0, 1>(acc, af, bf1);
      ldA(af, buf, 1);
      stageA(nb, 1, k0n);
      mfma_q<1, 1>(acc, af, bf1);
      mfma_q<1, 0>(acc, af, bf0);
      VMCNT(4); BAR();
    }
    {
      int buf = (KT - 1) & 1;
      ldA(af, buf, 0);
      ldB(bf0, buf, 0);
      mfma_q<0, 0>(acc, af, bf0);
      VMCNT(2); BAR();
      ldB(bf1, buf, 1);
      mfma_q<0, 1>(acc, af, bf1);
      VMCNT(0); BAR();
      ldA(af, buf, 1);
      mfma_q<1, 1>(acc, af, bf1);
      mfma_q<1, 0>(acc, af, bf0);
    }

    if (g == 2) {
      // V^T direct: Vt[bh][d][s]
      bf16* C = C2g;
#pragma unroll
      for (int mf = 0; mf < 8; ++mf)
#pragma unroll
        for (int nf = 0; nf < 4; ++nf) {
          int orow = r0 + wm * 128 + mf * 16 + lg * 4;
          int ocol = c0 + wn * 64 + nf * 16 + lr;
          int bh = ((orow >> 11) << 5) + (ocol >> 7);
          int d = ocol & 127;
          int sl = orow & 2047;
          bf16x4 v4 = {(bf16)acc[mf][nf][0], (bf16)acc[mf][nf][1],
                       (bf16)acc[mf][nf][2], (bf16)acc[mf][nf][3]};
          *(bf16x4*)(C + (size_t)bh * HD * S_ + (size_t)d * S_ + sl) = v4;
        }
    } else {
      bf16* C = (g == 0) ? C0g : C1g;
#pragma unroll
      for (int mf = 0; mf < 8; ++mf)
#pragma unroll
        for (int nf = 0; nf < 4; ++nf) {
          int orow = r0 + wm * 128 + mf * 16 + lg * 4;
          int ocol = c0 + wn * 64 + nf * 16 + lr;
#pragma unroll
          for (int jr = 0; jr < 4; ++jr)
            C[(size_t)(orow + jr) * N + ocol] = (bf16)acc[mf][nf][jr];
        }
    }
  }
}

// ---------------- 256x256 GEMM (single-tile, final Wo GEMM; r24-verified) ----------------
template <int EPI, int NC>
__global__ __launch_bounds__(512, 2) void gemm256(const bf16* __restrict__ A,
                                                  const bf16* __restrict__ B0g,
                                                  const bf16* __restrict__ B1g,
                                                  const bf16* __restrict__ B2g,
                                                  void* __restrict__ C0g,
                                                  void* __restrict__ C1g,
                                                  void* __restrict__ C2g) {
  constexpr int K = 4096, N = 4096, KT = K / 64;
  __shared__ __attribute__((aligned(16))) char lds[131072];
  char* Al = lds;
  char* Bl = lds + 65536;
  int tid = threadIdx.x;
  int l = tid & 63, lr = l & 15, lg = l >> 4;
  int w = tid >> 6, wm = w >> 2, wn = w & 3;
  int bid = (int)blockIdx.x;
  int x = bid & 7, local = bid >> 3;
  int lr0b = local / NC, lc0 = local % NC;
  int r0 = (x * 2 + lr0b) * 256;
  int g = lc0 >> 4;
  int c0 = (lc0 & 15) * 256;
  const bf16* Bw = (g == 0) ? B0g : ((g == 1) ? B1g : B2g);
  const bf16* Ab = A + (size_t)r0 * K;
  const bf16* Bb = Bw + (size_t)c0 * K;

  int lr0 = tid >> 3;
  int cel = (((tid & 7) ^ ((tid >> 3) & 7)) << 3);

  auto stageA = [&](int buf, int mh, int k0) {
    char* dst = Al + buf * 32768 + mh * 16384 + tid * 16;
    int ra = mh * 64 + lr0;
    gl_lds16(Ab + (size_t)ra * K + k0 + cel, dst);
    gl_lds16(Ab + (size_t)(ra + 128) * K + k0 + cel, dst + 8192);
  };
  auto stageB = [&](int buf, int nh, int k0) {
    char* dst = Bl + buf * 32768 + nh * 16384 + tid * 16;
    int n0 = (lr0 >> 5) * 64 + nh * 32 + (lr0 & 31);
    gl_lds16(Bb + (size_t)n0 * K + k0 + cel, dst);
    gl_lds16(Bb + (size_t)(n0 + 128) * K + k0 + cel, dst + 8192);
  };

  int rsw = (lr & 7) << 4;
  auto ldA = [&](bf16x8 (&dst)[4][2], int buf, int mh) {
    char* base = Al + buf * 32768 + mh * 16384 + wm * 8192;
#pragma unroll
    for (int mfl = 0; mfl < 4; ++mfl)
#pragma unroll
      for (int kf = 0; kf < 2; ++kf)
        __builtin_memcpy(&dst[mfl][kf],
                         base + (mfl * 16 + lr) * 128 + ((kf * 64 + lg * 16) ^ rsw), 16);
  };
  auto ldB = [&](bf16x8 (&dst)[2][2], int buf, int nh) {
    char* base = Bl + buf * 32768 + nh * 16384 + wn * 4096;
#pragma unroll
    for (int nfl = 0; nfl < 2; ++nfl)
#pragma unroll
      for (int kf = 0; kf < 2; ++kf)
        __builtin_memcpy(&dst[nfl][kf],
                         base + (nfl * 16 + lr) * 128 + ((kf * 64 + lg * 16) ^ rsw), 16);
  };

  bf16x8 af[4][2], bf0[2][2], bf1[2][2];
  f32x4 acc[8][4] = {};

  stageA(0, 0, 0);
  stageB(0, 0, 0);
  stageB(0, 1, 0);
  stageA(0, 1, 0);
  VMCNT(4); BAR();

  for (int kt = 0; kt < KT - 1; ++kt) {
    int buf = kt & 1, nb = buf ^ 1;
    int k0n = (kt + 1) * 64;
    ldA(af, buf, 0);
    ldB(bf0, buf, 0);
    stageA(nb, 0, k0n);
    stageB(nb, 0, k0n);
    mfma_q<0, 0>(acc, af, bf0);
    VMCNT(4); BAR();
    ldB(bf1, buf, 1);
    stageB(nb, 1, k0n);
    mfma_q<0, 1>(acc, af, bf1);
    ldA(af, buf, 1);
    stageA(nb, 1, k0n);
    mfma_q<1, 1>(acc, af, bf1);
    mfma_q<1, 0>(acc, af, bf0);
    VMCNT(4); BAR();
  }
  {
    int buf = (KT - 1) & 1;
    ldA(af, buf, 0);
    ldB(bf0, buf, 0);
    mfma_q<0, 0>(acc, af, bf0);
    VMCNT(2); BAR();
    ldB(bf1, buf, 1);
    mfma_q<0, 1>(acc, af, bf1);
    VMCNT(0); BAR();
    ldA(af, buf, 1);
    mfma_q<1, 1>(acc, af, bf1);
    mfma_q<1, 0>(acc, af, bf0);
  }

  void* Cg = (g == 0) ? C0g : ((g == 1) ? C1g : C2g);
#pragma unroll
  for (int mf = 0; mf < 8; ++mf)
#pragma unroll
    for (int nf = 0; nf < 4; ++nf) {
      int orow = r0 + wm * 128 + mf * 16 + lg * 4;
      int ocol = c0 + wn * 64 + nf * 16 + lr;
      if (EPI == 0) {
        bf16* C = (bf16*)Cg;
#pragma unroll
        for (int jr = 0; jr < 4; ++jr)
          C[(size_t)(orow + jr) * N + ocol] = (bf16)acc[mf][nf][jr];
      } else {
        float* C = (float*)Cg;
#pragma unroll
        for (int jr = 0; jr < 4; ++jr)
          C[(size_t)(orow + jr) * N + ocol] = acc[mf][nf][jr];
      }
    }
}

// ---------------- RoPE in-place, Q and K in one launch ----------------
__global__ __launch_bounds__(256) void rope_kernel(bf16* __restrict__ Qx,
                                                   bf16* __restrict__ Kx,
                                                   const int* __restrict__ pos,
                                                   float qscale) {
  int r = blockIdx.x;
  bf16* X = blockIdx.y ? Kx : Qx;
  float scale = blockIdx.y ? 1.0f : qscale;
  float pf = (float)pos[r];
  int i = threadIdx.x & 63;
  int h0 = threadIdx.x >> 6;
  float ang = pf * exp2f(-0.20762050593046868f * (float)i);
  float sn = sinf(ang), cs = cosf(ang);
  bf16* row = X + (size_t)r * H_;
#pragma unroll
  for (int h = h0; h < NH; h += 4) {
    bf16* p = row + h * HD + i;
    float a = (float)p[0], b = (float)p[64];
    p[0] = (bf16)((a * cs - b * sn) * scale);
    p[64] = (bf16)((b * cs + a * sn) * scale);
  }
}

// ---------------- causal flash attention (r20: 8-wave, XCD swizzle, deferred ls) ----------------
__global__ __launch_bounds__(512, 4) void attn_kernel(const bf16* __restrict__ Q,
                                                      const bf16* __restrict__ Km,
                                                      const bf16* __restrict__ Vt,
                                                      bf16* __restrict__ Out) {
  __shared__ __attribute__((aligned(16))) bf16 Ks[2][64 * 128];
  __shared__ __attribute__((aligned(16))) bf16 Vs[2][128 * 64];
  __shared__ __attribute__((aligned(16))) bf16 P_lds[8][16 * 64];
  int tid = threadIdx.x;
  int w = tid >> 6, l = tid & 63;
  int lr = l & 15, lg = l >> 4;
  int f = (int)(blockIdx.y * gridDim.x + blockIdx.x);
  int wk = (f & 7) * 128 + (f >> 3);  // XCD-grouped, bijective (1024 % 8 == 0)
  int bh = wk >> 4, b = bh >> 5, h = bh & 31;
  int qt = 15 - (wk & 15);            // heavy-first within each (b,h)
  int q0w = qt * 128 + w * 16;
  const bf16* Qb = Q + (size_t)b * S_ * H_ + h * HD;
  const char* Kg = (const char*)(Km + (size_t)b * S_ * H_ + h * HD);
  const char* Vg = (const char*)(Vt + (size_t)bh * HD * S_);
  bf16* Ob = Out + (size_t)b * S_ * H_ + h * HD;

  bf16x8 qf[4];
#pragma unroll
  for (int dk = 0; dk < 4; ++dk)
    __builtin_memcpy(&qf[dk], Qb + (size_t)(q0w + lr) * H_ + dk * 32 + lg * 8, 16);

  f32x4 o[8] = {};
  float m = -INFINITY, ls = 0.f;
  int nkv_blk = 2 * qt + 2;
  int nkv_w = 2 * qt + (w >> 2) + 1;

  auto stageK = [&](int buf, int kv0) {
#pragma unroll
    for (int p = 0; p < 2; ++p) {
      int row = p * 32 + (tid >> 4);
      int src = ((tid & 15) * 16) ^ ((row & 7) << 4);
      gl_lds16(Kg + (size_t)(kv0 + row) * (H_ * 2) + src,
               (char*)&Ks[buf][0] + p * 8192 + w * 1024);
    }
  };
  auto stageV = [&](int buf, int kv0) {
#pragma unroll
    for (int p = 0; p < 2; ++p) {
      int row = p * 64 + (tid >> 3);
      int src = ((tid & 7) * 16) ^ ((row & 7) << 4);
      gl_lds16(Vg + (size_t)row * (S_ * 2) + (size_t)kv0 * 2 + src,
               (char*)&Vs[buf][0] + p * 8192 + w * 1024);
    }
  };

  stageK(0, 0);
  stageV(0, 0);
  __syncthreads();

  int cur = 0;
  char* Pl = (char*)&P_lds[w][0];
  for (int t = 0; t < nkv_blk; ++t) {
    int kv0 = t * 64;
    if (t + 1 < nkv_blk) {
      stageK(cur ^ 1, kv0 + 64);
      stageV(cur ^ 1, kv0 + 64);
    }
    if (t < nkv_w) {
      const char* Kl = (const char*)&Ks[cur][0];
      const char* Vl = (const char*)&Vs[cur][0];
      f32x4 s4[4] = {};
      __builtin_amdgcn_s_setprio(1);
#pragma unroll
      for (int dk = 0; dk < 4; ++dk)
#pragma unroll
        for (int st = 0; st < 4; ++st) {
          int row = st * 16 + lr;
          int cb = (dk * 64 + lg * 16) ^ ((row & 7) << 4);
          bf16x8 kf;
          __builtin_memcpy(&kf, Kl + row * 256 + cb, 16);
          s4[st] = __builtin_amdgcn_mfma_f32_16x16x32_bf16(kf, qf[dk], s4[st], 0, 0, 0);
        }
      __builtin_amdgcn_s_setprio(0);
      if (t == nkv_w - 1) {
        int qg = q0w + lr;
#pragma unroll
        for (int st = 0; st < 4; ++st)
#pragma unroll
          for (int j = 0; j < 4; ++j)
            if (kv0 + st * 16 + lg * 4 + j > qg) s4[st][j] = -INFINITY;
      }
      float mx = -INFINITY;
#pragma unroll
      for (int st = 0; st < 4; ++st)
#pragma unroll
        for (int j = 0; j < 4; ++j) mx = fmaxf(mx, s4[st][j]);
      mx = fmaxf(mx, __shfl_xor(mx, 16));
      mx = fmaxf(mx, __shfl_xor(mx, 32));
      float sc = 1.0f;
      if (!__all((int)(mx <= m + 8.0f))) {
        float mn = fmaxf(m, mx);
        sc = exp2f(m - mn);
        m = mn;
        float scq0 = __shfl(sc, lg * 4 + 0);
        float scq1 = __shfl(sc, lg * 4 + 1);
        float scq2 = __shfl(sc, lg * 4 + 2);
        float scq3 = __shfl(sc, lg * 4 + 3);
#pragma unroll
        for (int dt = 0; dt < 8; ++dt) {
          o[dt][0] *= scq0; o[dt][1] *= scq1; o[dt][2] *= scq2; o[dt][3] *= scq3;
        }
      }
      float pv[4][4], rs = 0.f;
#pragma unroll
      for (int st = 0; st < 4; ++st)
#pragma unroll
        for (int j = 0; j < 4; ++j) {
          pv[st][j] = exp2f(s4[st][j] - m);
          rs += pv[st][j];
        }
      ls = ls * sc + rs;  // per-lane partial (sc row-uniform) -> exact
#pragma unroll
      for (int st = 0; st < 4; ++st) {
        bf16x4 pk = {(bf16)pv[st][0], (bf16)pv[st][1], (bf16)pv[st][2], (bf16)pv[st][3]};
        *(bf16x4*)(Pl + lr * 128 + ((st * 32 + lg * 8) ^ ((lr & 7) << 4))) = pk;
      }
      bf16x8 pa[2];
#pragma unroll
      for (int ks = 0; ks < 2; ++ks)
        __builtin_memcpy(&pa[ks], Pl + lr * 128 + ((ks * 64 + lg * 16) ^ ((lr & 7) << 4)), 16);
      __builtin_amdgcn_s_setprio(1);
#pragma unroll
      for (int dt = 0; dt < 8; ++dt)
#pragma unroll
        for (int ks = 0; ks < 2; ++ks) {
          int row = dt * 16 + lr;
          int cb = (ks * 64 + lg * 16) ^ ((row & 7) << 4);
          bf16x8 vf;
          __builtin_memcpy(&vf, Vl + row * 128 + cb, 16);
          o[dt] = __builtin_amdgcn_mfma_f32_16x16x32_bf16(pa[ks], vf, o[dt], 0, 0, 0);
        }
      __builtin_amdgcn_s_setprio(0);
    }
    __syncthreads();
    cur ^= 1;
  }
  ls += __shfl_xor(ls, 16);
  ls += __shfl_xor(ls, 32);
  float lsq[4];
#pragma unroll
  for (int j = 0; j < 4; ++j) lsq[j] = __shfl(ls, lg * 4 + j);
#pragma unroll
  for (int j = 0; j < 4; ++j) {
    float inv = 1.0f / lsq[j];
#pragma unroll
    for (int dt = 0; dt < 8; ++dt)
      Ob[(size_t)(q0w + lg * 4 + j) * H_ + dt * 16 + lr] = (bf16)(o[dt][j] * inv);
  }
}

extern "C" void kernel_launch(void* const* d_in, const int* in_sizes, int n_in,
                              void* d_out, int out_size, void* d_ws, size_t ws_size,
                              hipStream_t stream) {
  const float* X = (const float*)d_in[0];
  const int* pos = (const int*)d_in[2];
  const float* Wq = (const float*)d_in[3];
  const float* Wk = (const float*)d_in[4];
  const float* Wv = (const float*)d_in[5];
  const float* Wo = (const float*)d_in[6];
  float* out = (float*)d_out;
  char* ws = (char*)d_ws;
  const size_t MB32 = 32ull << 20;
  bf16* Xb = (bf16*)ws;               // X bf16; later attn output
  bf16* Wb = (bf16*)(ws + MB32);      // Wq bf16, later Wo bf16
  bf16* Qb = (bf16*)(ws + 2 * MB32);
  bf16* Kb = (bf16*)(ws + 3 * MB32);
  bf16* Vtb = (bf16*)(ws + 4 * MB32); // V^T written directly by the QKV GEMM
  bf16* Wkb = (bf16*)(ws + 5 * MB32); // Wk bf16 (read-only during QKV GEMM)
  bf16* Wvb = (bf16*)d_out;           // Wv bf16 parked in d_out (dead until final GEMM)

  const int n4 = (4096 * 4096) / 4;
  dim3 cblk(256);

  cast4_kernel<<<dim3(n4 / 256, 4), cblk, 0, stream>>>(X, Xb, Wq, Wb, Wk, Wkb, Wv, Wvb, n4);

  // persistent merged QKV GEMM: 256 blocks (1/CU), 3 col-tiles each
  gemm256_qkv<<<dim3(256), dim3(512), 0, stream>>>(Xb, Wb, Wkb, Wvb, Qb, Kb, Vtb);

  const float qscale = 1.4426950408889634f / 11.313708498984760f;  // log2(e)/sqrt(128)
  rope_kernel<<<dim3(4096, 2), 256, 0, stream>>>(Qb, Kb, pos, qscale);

  attn_kernel<<<dim3(16, 64), 512, 0, stream>>>(Qb, Kb, Vtb, Xb);

  cast_kernel<<<dim3(n4 / 256), cblk, 0, stream>>>(Wo, Wb, n4);
  gemm256<1, 16><<<dim3(256), dim3(512), 0, stream>>>(Xb, Wb, Wb, Wb, out, out, out);
}

// Round 27
// 745.393 us; speedup vs baseline: 1.0232x; 1.0232x over previous
//
#include <hip/hip_runtime.h>
#include <cstdint>
#include <cmath>

typedef __bf16 bf16;
typedef __bf16 bf16x8 __attribute__((ext_vector_type(8)));
typedef __bf16 bf16x4 __attribute__((ext_vector_type(4)));
typedef float f32x4 __attribute__((ext_vector_type(4)));

#define B_ 2
#define S_ 2048
#define H_ 4096
#define NH 32
#define HD 128

#define VMCNT(n) asm volatile("s_waitcnt vmcnt(" #n ")" ::: "memory")
#define BAR() __builtin_amdgcn_s_barrier()

__device__ __forceinline__ void gl_lds16(const void* g, void* l) {
  __builtin_amdgcn_global_load_lds(
      (const __attribute__((address_space(1))) unsigned int*)g,
      (__attribute__((address_space(3))) unsigned int*)l, 16, 0, 0);
}

// ---------------- fused cast f32 -> bf16 (4 tensors in one launch) ----------------
__global__ __launch_bounds__(256) void cast4_kernel(const float* __restrict__ s0,
                                                    bf16* __restrict__ d0,
                                                    const float* __restrict__ s1,
                                                    bf16* __restrict__ d1,
                                                    const float* __restrict__ s2,
                                                    bf16* __restrict__ d2,
                                                    const float* __restrict__ s3,
                                                    bf16* __restrict__ d3, int n4) {
  int g = blockIdx.y;
  const float* in = (g == 0) ? s0 : (g == 1) ? s1 : (g == 2) ? s2 : s3;
  bf16* out = (g == 0) ? d0 : (g == 1) ? d1 : (g == 2) ? d2 : d3;
  int i = blockIdx.x * 256 + threadIdx.x;
  if (i < n4) {
    float4 v = ((const float4*)in)[i];
    bf16x4 o = {(bf16)v.x, (bf16)v.y, (bf16)v.z, (bf16)v.w};
    ((bf16x4*)out)[i] = o;
  }
}

__global__ __launch_bounds__(256) void cast_kernel(const float* __restrict__ in,
                                                   bf16* __restrict__ out, int n4) {
  int i = blockIdx.x * 256 + threadIdx.x;
  if (i < n4) {
    float4 v = ((const float4*)in)[i];
    bf16x4 o = {(bf16)v.x, (bf16)v.y, (bf16)v.z, (bf16)v.w};
    ((bf16x4*)out)[i] = o;
  }
}

// ---------------- 256x256 GEMM (r25-verified; g==2 writes V^T directly) ----------------
template <int TM, int TN>
__device__ __forceinline__ void mfma_q(f32x4 (&acc)[8][4], bf16x8 (&a)[4][2],
                                       bf16x8 (&b)[2][2]) {
  __builtin_amdgcn_s_setprio(1);
#pragma unroll
  for (int i = 0; i < 4; ++i)
#pragma unroll
    for (int j = 0; j < 2; ++j)
#pragma unroll
      for (int kf = 0; kf < 2; ++kf)
        acc[TM * 4 + i][TN * 2 + j] = __builtin_amdgcn_mfma_f32_16x16x32_bf16(
            a[i][kf], b[j][kf], acc[TM * 4 + i][TN * 2 + j], 0, 0, 0);
  __builtin_amdgcn_s_setprio(0);
}

template <int EPI, int NC>
__global__ __launch_bounds__(512, 2) void gemm256(const bf16* __restrict__ A,
                                                  const bf16* __restrict__ B0g,
                                                  const bf16* __restrict__ B1g,
                                                  const bf16* __restrict__ B2g,
                                                  void* __restrict__ C0g,
                                                  void* __restrict__ C1g,
                                                  void* __restrict__ C2g) {
  constexpr int K = 4096, N = 4096, KT = K / 64;
  __shared__ __attribute__((aligned(16))) char lds[131072];
  char* Al = lds;
  char* Bl = lds + 65536;
  int tid = threadIdx.x;
  int l = tid & 63, lr = l & 15, lg = l >> 4;
  int w = tid >> 6, wm = w >> 2, wn = w & 3;
  int bid = (int)blockIdx.x;
  int x = bid & 7, local = bid >> 3;      // XCD-chunked: x owns 2 row-panels x NC cols
  int lr0b = local / NC, lc0 = local % NC;
  int r0 = (x * 2 + lr0b) * 256;
  int g = lc0 >> 4;
  int c0 = (lc0 & 15) * 256;
  const bf16* Bw = (g == 0) ? B0g : ((g == 1) ? B1g : B2g);
  const bf16* Ab = A + (size_t)r0 * K;
  const bf16* Bb = Bw + (size_t)c0 * K;

  int lr0 = tid >> 3;
  int cel = (((tid & 7) ^ ((tid >> 3) & 7)) << 3);

  auto stageA = [&](int buf, int mh, int k0) {
    char* dst = Al + buf * 32768 + mh * 16384 + tid * 16;
    int ra = mh * 64 + lr0;
    gl_lds16(Ab + (size_t)ra * K + k0 + cel, dst);
    gl_lds16(Ab + (size_t)(ra + 128) * K + k0 + cel, dst + 8192);
  };
  auto stageB = [&](int buf, int nh, int k0) {
    char* dst = Bl + buf * 32768 + nh * 16384 + tid * 16;
    int n0 = (lr0 >> 5) * 64 + nh * 32 + (lr0 & 31);
    gl_lds16(Bb + (size_t)n0 * K + k0 + cel, dst);
    gl_lds16(Bb + (size_t)(n0 + 128) * K + k0 + cel, dst + 8192);
  };

  int rsw = (lr & 7) << 4;
  auto ldA = [&](bf16x8 (&dst)[4][2], int buf, int mh) {
    char* base = Al + buf * 32768 + mh * 16384 + wm * 8192;
#pragma unroll
    for (int mfl = 0; mfl < 4; ++mfl)
#pragma unroll
      for (int kf = 0; kf < 2; ++kf)
        __builtin_memcpy(&dst[mfl][kf],
                         base + (mfl * 16 + lr) * 128 + ((kf * 64 + lg * 16) ^ rsw), 16);
  };
  auto ldB = [&](bf16x8 (&dst)[2][2], int buf, int nh) {
    char* base = Bl + buf * 32768 + nh * 16384 + wn * 4096;
#pragma unroll
    for (int nfl = 0; nfl < 2; ++nfl)
#pragma unroll
      for (int kf = 0; kf < 2; ++kf)
        __builtin_memcpy(&dst[nfl][kf],
                         base + (nfl * 16 + lr) * 128 + ((kf * 64 + lg * 16) ^ rsw), 16);
  };

  bf16x8 af[4][2], bf0[2][2], bf1[2][2];
  f32x4 acc[8][4] = {};

  stageA(0, 0, 0);
  stageB(0, 0, 0);
  stageB(0, 1, 0);
  stageA(0, 1, 0);
  VMCNT(4); BAR();

  for (int kt = 0; kt < KT - 1; ++kt) {
    int buf = kt & 1, nb = buf ^ 1;
    int k0n = (kt + 1) * 64;
    ldA(af, buf, 0);
    ldB(bf0, buf, 0);
    stageA(nb, 0, k0n);
    stageB(nb, 0, k0n);
    mfma_q<0, 0>(acc, af, bf0);
    VMCNT(4); BAR();
    ldB(bf1, buf, 1);
    stageB(nb, 1, k0n);
    mfma_q<0, 1>(acc, af, bf1);
    ldA(af, buf, 1);
    stageA(nb, 1, k0n);
    mfma_q<1, 1>(acc, af, bf1);
    mfma_q<1, 0>(acc, af, bf0);
    VMCNT(4); BAR();
  }
  {
    int buf = (KT - 1) & 1;
    ldA(af, buf, 0);
    ldB(bf0, buf, 0);
    mfma_q<0, 0>(acc, af, bf0);
    VMCNT(2); BAR();
    ldB(bf1, buf, 1);
    mfma_q<0, 1>(acc, af, bf1);
    VMCNT(0); BAR();
    ldA(af, buf, 1);
    mfma_q<1, 1>(acc, af, bf1);
    mfma_q<1, 0>(acc, af, bf0);
  }

  void* Cg = (g == 0) ? C0g : ((g == 1) ? C1g : C2g);
  if (EPI == 0 && g == 2) {
    // V^T direct: Vt[bh][d][s]
    bf16* C = (bf16*)Cg;
#pragma unroll
    for (int mf = 0; mf < 8; ++mf)
#pragma unroll
      for (int nf = 0; nf < 4; ++nf) {
        int orow = r0 + wm * 128 + mf * 16 + lg * 4;
        int ocol = c0 + wn * 64 + nf * 16 + lr;
        int bh = ((orow >> 11) << 5) + (ocol >> 7);
        int d = ocol & 127;
        int sl = orow & 2047;
        bf16x4 v4 = {(bf16)acc[mf][nf][0], (bf16)acc[mf][nf][1],
                     (bf16)acc[mf][nf][2], (bf16)acc[mf][nf][3]};
        *(bf16x4*)(C + (size_t)bh * HD * S_ + (size_t)d * S_ + sl) = v4;
      }
  } else {
#pragma unroll
    for (int mf = 0; mf < 8; ++mf)
#pragma unroll
      for (int nf = 0; nf < 4; ++nf) {
        int orow = r0 + wm * 128 + mf * 16 + lg * 4;
        int ocol = c0 + wn * 64 + nf * 16 + lr;
        if (EPI == 0) {
          bf16* C = (bf16*)Cg;
#pragma unroll
          for (int jr = 0; jr < 4; ++jr)
            C[(size_t)(orow + jr) * N + ocol] = (bf16)acc[mf][nf][jr];
        } else {
          float* C = (float*)Cg;
#pragma unroll
          for (int jr = 0; jr < 4; ++jr)
            C[(size_t)(orow + jr) * N + ocol] = acc[mf][nf][jr];
        }
      }
  }
}

// ---------------- RoPE in-place, Q and K in one launch ----------------
__global__ __launch_bounds__(256) void rope_kernel(bf16* __restrict__ Qx,
                                                   bf16* __restrict__ Kx,
                                                   const int* __restrict__ pos,
                                                   float qscale) {
  int r = blockIdx.x;
  bf16* X = blockIdx.y ? Kx : Qx;
  float scale = blockIdx.y ? 1.0f : qscale;
  float pf = (float)pos[r];
  int i = threadIdx.x & 63;
  int h0 = threadIdx.x >> 6;
  float ang = pf * exp2f(-0.20762050593046868f * (float)i);
  float sn = sinf(ang), cs = cosf(ang);
  bf16* row = X + (size_t)r * H_;
#pragma unroll
  for (int h = h0; h < NH; h += 4) {
    bf16* p = row + h * HD + i;
    float a = (float)p[0], b = (float)p[64];
    p[0] = (bf16)((a * cs - b * sn) * scale);
    p[64] = (bf16)((b * cs + a * sn) * scale);
  }
}

// ---------------- causal flash attention (r20: 8-wave, XCD swizzle, deferred ls) ----------------
__global__ __launch_bounds__(512, 4) void attn_kernel(const bf16* __restrict__ Q,
                                                      const bf16* __restrict__ Km,
                                                      const bf16* __restrict__ Vt,
                                                      bf16* __restrict__ Out) {
  __shared__ __attribute__((aligned(16))) bf16 Ks[2][64 * 128];
  __shared__ __attribute__((aligned(16))) bf16 Vs[2][128 * 64];
  __shared__ __attribute__((aligned(16))) bf16 P_lds[8][16 * 64];
  int tid = threadIdx.x;
  int w = tid >> 6, l = tid & 63;
  int lr = l & 15, lg = l >> 4;
  int f = (int)(blockIdx.y * gridDim.x + blockIdx.x);
  int wk = (f & 7) * 128 + (f >> 3);  // XCD-grouped, bijective (1024 % 8 == 0)
  int bh = wk >> 4, b = bh >> 5, h = bh & 31;
  int qt = 15 - (wk & 15);            // heavy-first within each (b,h)
  int q0w = qt * 128 + w * 16;
  const bf16* Qb = Q + (size_t)b * S_ * H_ + h * HD;
  const char* Kg = (const char*)(Km + (size_t)b * S_ * H_ + h * HD);
  const char* Vg = (const char*)(Vt + (size_t)bh * HD * S_);
  bf16* Ob = Out + (size_t)b * S_ * H_ + h * HD;

  bf16x8 qf[4];
#pragma unroll
  for (int dk = 0; dk < 4; ++dk)
    __builtin_memcpy(&qf[dk], Qb + (size_t)(q0w + lr) * H_ + dk * 32 + lg * 8, 16);

  f32x4 o[8] = {};
  float m = -INFINITY, ls = 0.f;
  int nkv_blk = 2 * qt + 2;
  int nkv_w = 2 * qt + (w >> 2) + 1;

  auto stageK = [&](int buf, int kv0) {
#pragma unroll
    for (int p = 0; p < 2; ++p) {
      int row = p * 32 + (tid >> 4);
      int src = ((tid & 15) * 16) ^ ((row & 7) << 4);
      gl_lds16(Kg + (size_t)(kv0 + row) * (H_ * 2) + src,
               (char*)&Ks[buf][0] + p * 8192 + w * 1024);
    }
  };
  auto stageV = [&](int buf, int kv0) {
#pragma unroll
    for (int p = 0; p < 2; ++p) {
      int row = p * 64 + (tid >> 3);
      int src = ((tid & 7) * 16) ^ ((row & 7) << 4);
      gl_lds16(Vg + (size_t)row * (S_ * 2) + (size_t)kv0 * 2 + src,
               (char*)&Vs[buf][0] + p * 8192 + w * 1024);
    }
  };

  stageK(0, 0);
  stageV(0, 0);
  __syncthreads();

  int cur = 0;
  char* Pl = (char*)&P_lds[w][0];
  for (int t = 0; t < nkv_blk; ++t) {
    int kv0 = t * 64;
    if (t + 1 < nkv_blk) {
      stageK(cur ^ 1, kv0 + 64);
      stageV(cur ^ 1, kv0 + 64);
    }
    if (t < nkv_w) {
      const char* Kl = (const char*)&Ks[cur][0];
      const char* Vl = (const char*)&Vs[cur][0];
      f32x4 s4[4] = {};
      __builtin_amdgcn_s_setprio(1);
#pragma unroll
      for (int dk = 0; dk < 4; ++dk)
#pragma unroll
        for (int st = 0; st < 4; ++st) {
          int row = st * 16 + lr;
          int cb = (dk * 64 + lg * 16) ^ ((row & 7) << 4);
          bf16x8 kf;
          __builtin_memcpy(&kf, Kl + row * 256 + cb, 16);
          s4[st] = __builtin_amdgcn_mfma_f32_16x16x32_bf16(kf, qf[dk], s4[st], 0, 0, 0);
        }
      __builtin_amdgcn_s_setprio(0);
      if (t == nkv_w - 1) {
        int qg = q0w + lr;
#pragma unroll
        for (int st = 0; st < 4; ++st)
#pragma unroll
          for (int j = 0; j < 4; ++j)
            if (kv0 + st * 16 + lg * 4 + j > qg) s4[st][j] = -INFINITY;
      }
      float mx = -INFINITY;
#pragma unroll
      for (int st = 0; st < 4; ++st)
#pragma unroll
        for (int j = 0; j < 4; ++j) mx = fmaxf(mx, s4[st][j]);
      mx = fmaxf(mx, __shfl_xor(mx, 16));
      mx = fmaxf(mx, __shfl_xor(mx, 32));
      float sc = 1.0f;
      if (!__all((int)(mx <= m + 8.0f))) {
        float mn = fmaxf(m, mx);
        sc = exp2f(m - mn);
        m = mn;
        float scq0 = __shfl(sc, lg * 4 + 0);
        float scq1 = __shfl(sc, lg * 4 + 1);
        float scq2 = __shfl(sc, lg * 4 + 2);
        float scq3 = __shfl(sc, lg * 4 + 3);
#pragma unroll
        for (int dt = 0; dt < 8; ++dt) {
          o[dt][0] *= scq0; o[dt][1] *= scq1; o[dt][2] *= scq2; o[dt][3] *= scq3;
        }
      }
      float pv[4][4], rs = 0.f;
#pragma unroll
      for (int st = 0; st < 4; ++st)
#pragma unroll
        for (int j = 0; j < 4; ++j) {
          pv[st][j] = exp2f(s4[st][j] - m);
          rs += pv[st][j];
        }
      ls = ls * sc + rs;  // per-lane partial (sc row-uniform) -> exact
#pragma unroll
      for (int st = 0; st < 4; ++st) {
        bf16x4 pk = {(bf16)pv[st][0], (bf16)pv[st][1], (bf16)pv[st][2], (bf16)pv[st][3]};
        *(bf16x4*)(Pl + lr * 128 + ((st * 32 + lg * 8) ^ ((lr & 7) << 4))) = pk;
      }
      bf16x8 pa[2];
#pragma unroll
      for (int ks = 0; ks < 2; ++ks)
        __builtin_memcpy(&pa[ks], Pl + lr * 128 + ((ks * 64 + lg * 16) ^ ((lr & 7) << 4)), 16);
      __builtin_amdgcn_s_setprio(1);
#pragma unroll
      for (int dt = 0; dt < 8; ++dt)
#pragma unroll
        for (int ks = 0; ks < 2; ++ks) {
          int row = dt * 16 + lr;
          int cb = (ks * 64 + lg * 16) ^ ((row & 7) << 4);
          bf16x8 vf;
          __builtin_memcpy(&vf, Vl + row * 128 + cb, 16);
          o[dt] = __builtin_amdgcn_mfma_f32_16x16x32_bf16(pa[ks], vf, o[dt], 0, 0, 0);
        }
      __builtin_amdgcn_s_setprio(0);
    }
    __syncthreads();
    cur ^= 1;
  }
  ls += __shfl_xor(ls, 16);
  ls += __shfl_xor(ls, 32);
  float lsq[4];
#pragma unroll
  for (int j = 0; j < 4; ++j) lsq[j] = __shfl(ls, lg * 4 + j);
#pragma unroll
  for (int j = 0; j < 4; ++j) {
    float inv = 1.0f / lsq[j];
#pragma unroll
    for (int dt = 0; dt < 8; ++dt)
      Ob[(size_t)(q0w + lg * 4 + j) * H_ + dt * 16 + lr] = (bf16)(o[dt][j] * inv);
  }
}

extern "C" void kernel_launch(void* const* d_in, const int* in_sizes, int n_in,
                              void* d_out, int out_size, void* d_ws, size_t ws_size,
                              hipStream_t stream) {
  const float* X = (const float*)d_in[0];
  const int* pos = (const int*)d_in[2];
  const float* Wq = (const float*)d_in[3];
  const float* Wk = (const float*)d_in[4];
  const float* Wv = (const float*)d_in[5];
  const float* Wo = (const float*)d_in[6];
  float* out = (float*)d_out;
  char* ws = (char*)d_ws;
  const size_t MB32 = 32ull << 20;
  bf16* Xb = (bf16*)ws;               // X bf16; later attn output
  bf16* Wb = (bf16*)(ws + MB32);      // Wq bf16, later Wo bf16
  bf16* Qb = (bf16*)(ws + 2 * MB32);
  bf16* Kb = (bf16*)(ws + 3 * MB32);
  bf16* Vtb = (bf16*)(ws + 4 * MB32); // V^T written directly by the QKV GEMM
  bf16* Wkb = (bf16*)(ws + 5 * MB32); // Wk bf16 (read-only during QKV GEMM)
  bf16* Wvb = (bf16*)d_out;           // Wv bf16 parked in d_out (dead until final GEMM)

  const int n4 = (4096 * 4096) / 4;
  dim3 cblk(256);

  cast4_kernel<<<dim3(n4 / 256, 4), cblk, 0, stream>>>(X, Xb, Wq, Wb, Wk, Wkb, Wv, Wvb, n4);

  // merged QKV GEMM: g=0->Q (Wb), g=1->K (Wkb), g=2->V^T direct (Vtb)
  gemm256<0, 48><<<dim3(768), dim3(512), 0, stream>>>(Xb, Wb, Wkb, Wvb, Qb, Kb, Vtb);

  const float qscale = 1.4426950408889634f / 11.313708498984760f;  // log2(e)/sqrt(128)
  rope_kernel<<<dim3(4096, 2), 256, 0, stream>>>(Qb, Kb, pos, qscale);

  attn_kernel<<<dim3(16, 64), 512, 0, stream>>>(Qb, Kb, Vtb, Xb);

  cast_kernel<<<dim3(n4 / 256), cblk, 0, stream>>>(Wo, Wb, n4);
  gemm256<1, 16><<<dim3(256), dim3(512), 0, stream>>>(Xb, Wb, Wb, Wb, out, out, out);
}